// Round 7
// baseline (366.770 us; speedup 1.0000x reference)
//
#include <hip/hip_runtime.h>
#include <stddef.h>
#include <stdint.h>

#define B_   32
#define IN_  4096
#define OUT_ 14336
#define NSEC 8           // 8 sections of 512 k
#define SECK 512
#define ROWSTRIDE 67     // padded dwords/row: phase-2 banks <=2-way (free)

typedef _Float16 v2h __attribute__((ext_vector_type(2)));
typedef _Float16 v8h __attribute__((ext_vector_type(8)));
typedef float    v4f __attribute__((ext_vector_type(4)));
typedef int      v4i __attribute__((ext_vector_type(4)));

__device__ __constant__ float c_nf4[16] = {
    -1.0f, -0.6961928009986877f, -0.5250730514526367f, -0.39491748809814453f,
    -0.28444138169288635f, -0.18477343022823334f, -0.09105003625154495f, 0.0f,
    0.07958029955625534f, 0.16093020141124725f, 0.24611230194568634f,
    0.33791524171829224f, 0.44070982933044434f, 0.5626170039176941f,
    0.7229568362236023f, 1.0f};

// x[32][4096] f32 -> xB f16 in B-fragment layout for mfma_f32_16x16x32_f16.
// Fragment t = (kt*2 + bt)*64 + l holds B[k = kt*32 + (l>>4)*8 + j][n = bt*16 + (l&15)]
__global__ __launch_bounds__(256) void prep(const float* __restrict__ x,
                                            unsigned* __restrict__ xB) {
    int t  = blockIdx.x * 256 + threadIdx.x;   // 0..16383
    int kt = t >> 7;
    int bt = (t >> 6) & 1;
    int l  = t & 63;
    int b  = bt * 16 + (l & 15);
    int k0 = kt * 32 + (l >> 4) * 8;
    const float* xr = x + (size_t)b * IN_ + k0;
    float4 a = *(const float4*)xr;
    float4 c = *(const float4*)(xr + 4);
    union { v2h h; unsigned u; } p0, p1, p2, p3;
    p0.h = (v2h){(_Float16)a.x, (_Float16)a.y};
    p1.h = (v2h){(_Float16)a.z, (_Float16)a.w};
    p2.h = (v2h){(_Float16)c.x, (_Float16)c.y};
    p3.h = (v2h){(_Float16)c.z, (_Float16)c.w};
    uint4 w = {p0.u, p1.u, p2.u, p3.u};
    *(uint4*)(xB + (size_t)t * 4) = w;
}

// Grid 224 x 256 (4 waves). Wave w: o-rows [blk*64 + w*16, +16), FULL K=4096
// as 8 sections of 512 k. Per section: stage 16 rows x 512 codes into
// wave-private LDS (contiguous nt 32 B/lane reads, packed to pair-bytes),
// then 16 MFMA steps (pair-LUT dequant, B-frags from xB). Direct out+bias
// epilogue: no partials, no reduce, no extra dispatches. Single barrier
// (lut2 init); wave reads only its own LDS writes.
__global__ __launch_bounds__(256) void nf4_mfma(
    const int* __restrict__ codes, const float* __restrict__ absmax,
    const unsigned* __restrict__ xB, const float* __restrict__ bias,
    float* __restrict__ out) {
    __shared__ unsigned stage[4 * 16 * ROWSTRIDE];
    __shared__ v2h lut2[256];

    const int tid = threadIdx.x;
    {   // lut2[b] = {nf4[b&15], nf4[b>>4]} : byte = even | odd<<4
        float lo = c_nf4[tid & 15], hi = c_nf4[tid >> 4];
        lut2[tid] = (v2h){(_Float16)lo, (_Float16)hi};
    }
    __syncthreads();   // only barrier; protects lut2

    const int w  = tid >> 6;
    const int l  = tid & 63;
    const int m  = l & 15;
    const int q  = l >> 4;
    const int o0 = blockIdx.x * 64 + w * 16;

    unsigned* sw = stage + w * 16 * ROWSTRIDE;
    const float* amrow = absmax + (size_t)(o0 + m) * 64;
    const uint4* xbp   = (const uint4*)xB + l;

    v4f acc0 = {0.f, 0.f, 0.f, 0.f};
    v4f acc1 = {0.f, 0.f, 0.f, 0.f};

#pragma unroll 1
    for (int s = 0; s < NSEC; ++s) {
        // ---- Phase 1: stage this section's codes (contiguous nt reads) ----
#pragma unroll
        for (int i = 0; i < 16; ++i) {
            const v4i* rp = (const v4i*)(codes + (size_t)(o0 + i) * IN_ + s * SECK);
            v4i a0 = __builtin_nontemporal_load(rp + 2 * l);
            v4i a1 = __builtin_nontemporal_load(rp + 2 * l + 1);
            unsigned pk = (unsigned)(a0[0] | (a0[1] << 4)) |
                          ((unsigned)(a0[2] | (a0[3] << 4)) << 8) |
                          ((unsigned)(a1[0] | (a1[1] << 4)) << 16) |
                          ((unsigned)(a1[2] | (a1[3] << 4)) << 24);
            sw[i * ROWSTRIDE + l] = pk;   // dword = codes [8l, 8l+8) of row i
        }

        // 8 absmax scales for this section (two float4 register loads)
        float4 amlo = *(const float4*)(amrow + s * 8);
        float4 amhi = *(const float4*)(amrow + s * 8 + 4);
        const float ams[8] = {amlo.x, amlo.y, amlo.z, amlo.w,
                              amhi.x, amhi.y, amhi.z, amhi.w};

        // ---- Phase 2: 16 MFMA k-steps ----
#pragma unroll
        for (int kt = 0; kt < 16; ++kt) {
            unsigned pk = sw[m * ROWSTRIDE + kt * 4 + q];   // codes [32kt+8q, +8)
            uint4 b0 = xbp[(size_t)(s * 16 + kt) * 128];
            uint4 b1 = xbp[(size_t)(s * 16 + kt) * 128 + 64];
            _Float16 ah = (_Float16)ams[kt >> 1];
            v2h amh = (v2h){ah, ah};

            union { v2h h[4]; v8h v; } A;
            A.h[0] = lut2[pk & 255] * amh;
            A.h[1] = lut2[(pk >> 8) & 255] * amh;
            A.h[2] = lut2[(pk >> 16) & 255] * amh;
            A.h[3] = lut2[pk >> 24] * amh;

            union { uint4 u; v8h v; } F0, F1;
            F0.u = b0;
            F1.u = b1;
            acc0 = __builtin_amdgcn_mfma_f32_16x16x32_f16(A.v, F0.v, acc0, 0, 0, 0);
            acc1 = __builtin_amdgcn_mfma_f32_16x16x32_f16(A.v, F1.v, acc1, 0, 0, 0);
        }
    }

    // D layout: col = l&15 (= batch within b-tile), row = q*4 + r (= o offset)
    const int bc = l & 15;
    const int ob = o0 + q * 4;
#pragma unroll
    for (int r = 0; r < 4; ++r) {
        float bv = bias[ob + r];
        out[(size_t)bc * OUT_ + ob + r]        = acc0[r] + bv;
        out[(size_t)(bc + 16) * OUT_ + ob + r] = acc1[r] + bv;
    }
}

extern "C" void kernel_launch(void* const* d_in, const int* in_sizes, int n_in,
                              void* d_out, int out_size, void* d_ws, size_t ws_size,
                              hipStream_t stream) {
    const float* x      = (const float*)d_in[0];
    const int*   codes  = (const int*)d_in[1];
    const float* absmax = (const float*)d_in[2];
    const float* bias   = (const float*)d_in[3];
    float* out = (float*)d_out;
    unsigned* xB = (unsigned*)d_ws;   // 256 KB

    prep<<<dim3(64), 256, 0, stream>>>(x, xB);
    nf4_mfma<<<dim3(OUT_ / 64), 256, 0, stream>>>(codes, absmax, xB, bias, out);
}

// Round 8
// 327.490 us; speedup vs baseline: 1.1199x; 1.1199x over previous
//
#include <hip/hip_runtime.h>
#include <stddef.h>
#include <stdint.h>

#define B_   32
#define IN_  4096
#define OUT_ 14336

typedef short v8s __attribute__((ext_vector_type(8)));
typedef float v4f __attribute__((ext_vector_type(4)));

__device__ __constant__ float c_nf4[16] = {
    -1.0f, -0.6961928009986877f, -0.5250730514526367f, -0.39491748809814453f,
    -0.28444138169288635f, -0.18477343022823334f, -0.09105003625154495f, 0.0f,
    0.07958029955625534f, 0.16093020141124725f, 0.24611230194568634f,
    0.33791524171829224f, 0.44070982933044434f, 0.5626170039176941f,
    0.7229568362236023f, 1.0f};

__device__ __forceinline__ unsigned f2bf_u(float f) {
    union { float f; unsigned u; } v; v.f = f;
    return (v.u + 0x7FFFu + ((v.u >> 16) & 1u)) >> 16;   // RNE, no NaN inputs
}
__device__ __forceinline__ unsigned pack2(float lo, float hi) {
    return f2bf_u(lo) | (f2bf_u(hi) << 16);
}

// x[32][4096] f32 -> xB bf16 in B-fragment layout for mfma_f32_16x16x32_bf16.
// Fragment t = (kt*2 + bt)*64 + l holds B[k = kt*32 + (l>>4)*8 + j][n = bt*16 + (l&15)]
__global__ __launch_bounds__(256) void prep(const float* __restrict__ x,
                                            unsigned* __restrict__ xB) {
    int t  = blockIdx.x * 256 + threadIdx.x;   // 0..16383
    int kt = t >> 7;
    int bt = (t >> 6) & 1;
    int l  = t & 63;
    int b  = bt * 16 + (l & 15);
    int k0 = kt * 32 + (l >> 4) * 8;
    const float* xr = x + (size_t)b * IN_ + k0;
    float4 a = *(const float4*)xr;
    float4 c = *(const float4*)(xr + 4);
    uint4 w;
    w.x = pack2(a.x, a.y);
    w.y = pack2(a.z, a.w);
    w.z = pack2(c.x, c.y);
    w.w = pack2(c.z, c.w);
    *(uint4*)(xB + (size_t)t * 4) = w;
}

// Grid 224 x 256 (4 waves). Wave w: o-rows [blk*64 + w*16, +16), full K=4096.
// Flat K-loop, unroll 8: per step 2 codes dwordx4 + 2 xB dwordx4 (L2-resident)
// -> dequant (lut + bf16 pack) -> 2 MFMA. No LDS staging, no barriers in loop,
// no K-split/partials. Direct out = acc + bias epilogue.
__global__ __launch_bounds__(256) void nf4_mfma(
    const int* __restrict__ codes, const float* __restrict__ absmax,
    const unsigned* __restrict__ xB, const float* __restrict__ bias,
    float* __restrict__ out) {
    __shared__ float lut[16];
    if (threadIdx.x < 16) lut[threadIdx.x] = c_nf4[threadIdx.x];
    __syncthreads();

    const int w  = threadIdx.x >> 6;
    const int l  = threadIdx.x & 63;
    const int o0 = blockIdx.x * 64 + w * 16;
    const int m  = l & 15;
    const int q  = l >> 4;

    const int*   crow  = codes + (size_t)(o0 + m) * IN_ + q * 8;
    const float* amrow = absmax + (size_t)(o0 + m) * 64;
    const uint4* xbp   = (const uint4*)xB + l;   // + (kt*2+bt)*64

    v4f acc0 = {0.f, 0.f, 0.f, 0.f};
    v4f acc1 = {0.f, 0.f, 0.f, 0.f};

#pragma unroll 8
    for (int kt = 0; kt < 128; ++kt) {
        int4 c0 = *(const int4*)(crow + (size_t)kt * 32);
        int4 c1 = *(const int4*)(crow + (size_t)kt * 32 + 4);
        uint4 b0 = xbp[(size_t)kt * 128];        // b-tile 0
        uint4 b1 = xbp[(size_t)kt * 128 + 64];   // b-tile 1
        float am = amrow[kt >> 1];               // 64-k absmax block

        union { uint4 u; v8s v; } a, f0, f1;
        a.u.x = pack2(lut[c0.x] * am, lut[c0.y] * am);
        a.u.y = pack2(lut[c0.z] * am, lut[c0.w] * am);
        a.u.z = pack2(lut[c1.x] * am, lut[c1.y] * am);
        a.u.w = pack2(lut[c1.z] * am, lut[c1.w] * am);
        f0.u = b0;
        f1.u = b1;
        acc0 = __builtin_amdgcn_mfma_f32_16x16x32_bf16(a.v, f0.v, acc0, 0, 0, 0);
        acc1 = __builtin_amdgcn_mfma_f32_16x16x32_bf16(a.v, f1.v, acc1, 0, 0, 0);
    }

    // D layout: col = l&15 (= batch within b-tile), row = q*4 + r (= o offset)
    const int bc = l & 15;
    const int ob = o0 + q * 4;
#pragma unroll
    for (int r = 0; r < 4; ++r) {
        float bv = bias[ob + r];
        out[(size_t)bc * OUT_ + ob + r]        = acc0[r] + bv;
        out[(size_t)(bc + 16) * OUT_ + ob + r] = acc1[r] + bv;
    }
}

extern "C" void kernel_launch(void* const* d_in, const int* in_sizes, int n_in,
                              void* d_out, int out_size, void* d_ws, size_t ws_size,
                              hipStream_t stream) {
    const float* x      = (const float*)d_in[0];
    const int*   codes  = (const int*)d_in[1];
    const float* absmax = (const float*)d_in[2];
    const float* bias   = (const float*)d_in[3];
    float* out = (float*)d_out;
    unsigned* xB = (unsigned*)d_ws;   // 256 KB

    prep<<<dim3(64), 256, 0, stream>>>(x, xB);
    nf4_mfma<<<dim3(OUT_ / 64), 256, 0, stream>>>(codes, absmax, xB, bias, out);
}